// Round 10
// baseline (486.071 us; speedup 1.0000x reference)
//
#include <hip/hip_runtime.h>
#include <stdint.h>
#include <stddef.h>

// CapsuleFC: B=64, N_IN=2048, D_IN=16, N_OUT=64, D_OUT=16
constexpr int B_ = 64, N_ = 2048, A_ = 16, M_ = 64, D_ = 16;
constexpr float SCALE_ = 0.25f;   // 1/sqrt(16)
constexpr float EPS_ = 1e-6f;

typedef float f32x4 __attribute__((ext_vector_type(4)));

#define GL16(g, l)                                                             \
  __builtin_amdgcn_global_load_lds((__attribute__((address_space(1))) void*)(g), \
                                   (__attribute__((address_space(3))) void*)(l), \
                                   16, 0, 0)

// counted vmcnt (literal); never 0 inside the steady loop (T4)
#define WV(n) asm volatile("s_waitcnt vmcnt(" #n ")" ::: "memory")
#define BAR() do {                        \
    asm volatile("" ::: "memory");        \
    __builtin_amdgcn_s_barrier();         \
    asm volatile("" ::: "memory");        \
    __builtin_amdgcn_sched_barrier(0);    \
  } while (0)

// grid: 4*nch blocks. block: 256 threads = 4 waves; wave wv owns 4 batches;
// lane l owns out-capsule m = l (wave-local softmax).
//
// R8 evidence: VGPR_Count=128 -> real residency 2 blocks/CU (unified
// VGPR+AGPR file doubles the allocation; occupancy pinned ~22%), and the
// per-half vmcnt(0) drain at __syncthreads is exposed -> VALUBusy 23%.
// R10 = R8 + m201-style pipeline: double-buffered 32KB halves, raw
// s_barrier, COUNTED vmcnt (stage(h+1) stays in flight across compute(h)).
// LDS 64KB -> 2 blocks/CU = same residency as the register cap: no loss.
__global__ __launch_bounds__(256, 2)
void caps_main(
    const float* __restrict__ input,   // [B,N,A]
    const float* __restrict__ cact,    // [B,N]
    const float* __restrict__ ncv,     // [B,M,D]
    const float* __restrict__ nact,    // [B,M]
    const float* __restrict__ w,       // [N,A,M,D]
    float* __restrict__ qk_out,        // [B,N,M]
    float* __restrict__ partial,       // [nch,B,M,D]
    int C, int nch)
{
  __shared__ __align__(128) char wl[2][32768];  // double-buffered a-half slabs

  const int tid  = threadIdx.x;
  const int lane = tid & 63;
  const int wv   = __builtin_amdgcn_readfirstlane(tid >> 6);

  // co-XCD mapping: the 4 bgroup-sharers of chunk ch land on xcd = flat&7
  const int flat = blockIdx.x;
  int bg, ch;
  if (nch & 7) { bg = flat & 3; ch = flat >> 2; }
  else { bg = (flat >> 3) & 3; ch = ((flat >> 5) << 3) | (flat & 7); }

  const int b0 = bg * 16 + wv * 4;
  const int n0 = ch * C;

  // swizzled LDS read offsets (pairs with stage-side source involution:
  // bits[6:4] ^= bits[9:7])
  int offj[4];
#pragma unroll
  for (int j = 0; j < 4; ++j)
    offj[j] = (lane * 64 + j * 16) ^ (((lane >> 1) & 7) << 4);

  // loop-invariant per-(b,m) values in registers
  float na[4], cv[4][16];
#pragma unroll
  for (int bi = 0; bi < 4; ++bi) {
    na[bi] = nact[(b0 + bi) * M_ + lane];
    const f32x4* np4 = (const f32x4*)(ncv + ((size_t)(b0 + bi) * M_ + lane) * D_);
#pragma unroll
    for (int j = 0; j < 4; ++j) {
      const f32x4 t = np4[j];
      cv[bi][4*j+0] = t.x; cv[bi][4*j+1] = t.y;
      cv[bi][4*j+2] = t.z; cv[bi][4*j+3] = t.w;
    }
  }
  // pin cv/na materialization pre-loop so no vmcnt wait sinks into the loop
  {
    float pin = 0.f;
#pragma unroll
    for (int bi = 0; bi < 4; ++bi) {
      pin += na[bi];
#pragma unroll
      for (int d = 0; d < 16; ++d) pin += cv[bi][d];
    }
    asm volatile("" :: "v"(pin));
    asm volatile("s_waitcnt vmcnt(0) lgkmcnt(0)" ::: "memory");
  }

  float acc[4][16];
#pragma unroll
  for (int bi = 0; bi < 4; ++bi)
#pragma unroll
    for (int d = 0; d < 16; ++d) acc[bi][d] = 0.f;

  // stage half h (32KB = 8 a-planes of w[n0 + h/2]) into wl[h&1]
  auto STAGE = [&](int h) {
    const int n = n0 + (h >> 1);
    const char* ws = (const char*)w + ((size_t)n << 16) + ((size_t)(h & 1) << 15);
    char* lb = (char*)wl[h & 1] + wv * 1024;
#pragma unroll
    for (int i = 0; i < 8; ++i) {
      const uint32_t P = (uint32_t)(i * 4096 + tid * 16);
      const uint32_t S = P ^ (((P >> 7) & 7u) << 4);
      GL16(ws + S, lb + i * 4096);
    }
  };

  float v[4][16];

  // compute half h from wl[h&1]; odd halves finish score+softmax+acc
  auto COMPUTE = [&](int h) {
    const int n  = n0 + (h >> 1);
    const int ah = h & 1;
    const char* lb = (const char*)wl[ah];
    if (ah == 0) {
#pragma unroll
      for (int bi = 0; bi < 4; ++bi)
#pragma unroll
        for (int d = 0; d < 16; ++d) v[bi][d] = 0.f;
    }
    // input half-rows: wave-uniform -> s_load (lgkmcnt; outside vmcnt window)
    float ib[4][8];
#pragma unroll
    for (int bi = 0; bi < 4; ++bi) {
      const int ibase = __builtin_amdgcn_readfirstlane(
          ((b0 + bi) * N_ + n) * A_ + ah * 8);
      const f32x4 r0 = *(const f32x4*)(input + ibase);
      const f32x4 r1 = *(const f32x4*)(input + ibase + 4);
      ib[bi][0] = r0.x; ib[bi][1] = r0.y; ib[bi][2] = r0.z; ib[bi][3] = r0.w;
      ib[bi][4] = r1.x; ib[bi][5] = r1.y; ib[bi][6] = r1.z; ib[bi][7] = r1.w;
    }
#pragma unroll
    for (int al = 0; al < 8; ++al) {
      f32x4 wr[4];
#pragma unroll
      for (int j = 0; j < 4; ++j)
        wr[j] = *(const f32x4*)(lb + al * 4096 + offj[j]);
#pragma unroll
      for (int bi = 0; bi < 4; ++bi) {
        const float x = ib[bi][al];
#pragma unroll
        for (int j = 0; j < 4; ++j) {
          v[bi][4*j+0] += x * wr[j].x; v[bi][4*j+1] += x * wr[j].y;
          v[bi][4*j+2] += x * wr[j].z; v[bi][4*j+3] += x * wr[j].w;
        }
      }
    }
    if (ah == 1) {
#pragma unroll
      for (int bi = 0; bi < 4; ++bi) {
        float s = 0.f;
#pragma unroll
        for (int d = 0; d < 16; ++d) s += v[bi][d] * cv[bi][d];
        s *= SCALE_;
        // |s| small (~N(0,0.2)); max-subtraction cancels in the ratio -> skip
        const float e = __expf(s);
        const float ena = e * na[bi];
        float Ps = ena;
#pragma unroll
        for (int off = 32; off >= 1; off >>= 1) Ps += __shfl_xor(Ps, off, 64);
        const float qk = ena / Ps;   // 1e-10 terms ~2e-10 relative: dropped
        qk_out[((size_t)(b0 + bi) * N_ + n) * M_ + lane] = qk;  // 4 stores/n
        float ab = cact[__builtin_amdgcn_readfirstlane((b0 + bi) * N_ + n)];
        ab = fminf(fmaxf(ab, EPS_), 1.0f - EPS_);
        const float wq = qk * ab;
#pragma unroll
        for (int d = 0; d < 16; ++d) acc[bi][d] += wq * v[bi][d];
      }
    }
  };

  // ---- pipelined loop. vmcnt ledger (issue order: [stage(h)8][4 stores?][stage(h+1)8]):
  //   peel k=0:  A: out={s0:8,s1:8}        -> WV(8)  retires s0
  //              B: out={s1:8,s2:8}        -> WV(8)  retires s1
  //   steady k:  A: out={s:8,st:4,s':8}=20 -> WV(12) retires stage, keeps stores
  //              B: out={st:4,s':8,s'':8}  -> WV(8)  retires stores+stage
  //   tail:      A: WV(12);  B: out={st:4,s_last:8} -> WV(0)
  STAGE(0);
  STAGE(1);
  // k = 0 (peeled)
  WV(8);  BAR(); COMPUTE(0); BAR(); STAGE(2);
  WV(8);  BAR(); COMPUTE(1); BAR(); STAGE(3);
  for (int k = 1; k < C - 1; ++k) {
    WV(12); BAR(); COMPUTE(2 * k);     BAR(); STAGE(2 * k + 2);
    WV(8);  BAR(); COMPUTE(2 * k + 1); BAR(); STAGE(2 * k + 3);
  }
  // k = C-1 (tail)
  WV(12); BAR(); COMPUTE(2 * C - 2); BAR();
  WV(0);  BAR(); COMPUTE(2 * C - 1); BAR();

  // partial[ch][b][m][d]
#pragma unroll
  for (int bi = 0; bi < 4; ++bi) {
    float* pp = partial + (((size_t)ch * B_ + (b0 + bi)) * M_ + lane) * D_;
#pragma unroll
    for (int j = 0; j < 4; ++j) {
      f32x4 t;
      t.x = acc[bi][4*j+0]; t.y = acc[bi][4*j+1];
      t.z = acc[bi][4*j+2]; t.w = acc[bi][4*j+3];
      __builtin_nontemporal_store(t, (f32x4*)pp + j);
    }
  }
}

__global__ void caps_reduce(const float* __restrict__ part,
                            const float* __restrict__ nain,
                            float* __restrict__ out, int nch)
{
  const int i = blockIdx.x * 256 + threadIdx.x;  // one thread per out[b,m,d]
  float s = 0.f;
  for (int c = 0; c < nch; ++c) s += part[(size_t)c * (B_ * M_ * D_) + i];
  out[i] = s;
  if (i < B_ * M_) out[B_ * M_ * D_ + i] = nain[i];  // next_act passthrough
}

extern "C" void kernel_launch(void* const* d_in, const int* in_sizes, int n_in,
                              void* d_out, int out_size, void* d_ws, size_t ws_size,
                              hipStream_t stream)
{
  const float* input = (const float*)d_in[0];
  const float* cact  = (const float*)d_in[1];
  const float* ncv   = (const float*)d_in[2];
  const float* nact  = (const float*)d_in[3];
  const float* w     = (const float*)d_in[4];

  float* out     = (float*)d_out;
  float* qk_out  = out + (B_ * M_ * D_) + (B_ * M_);   // after out and next_act
  float* partial = (float*)d_ws;

  // nch=256 -> grid 1024; needs 67MB ws; degrade if smaller (C>=2 required)
  int nch = 256;
  while ((size_t)nch * (size_t)(B_ * M_ * D_) * sizeof(float) > ws_size && nch > 32) nch >>= 1;
  const int C = N_ / nch;

  hipLaunchKernelGGL(caps_main, dim3(4 * nch), dim3(256), 0, stream,
                     input, cact, ncv, nact, w, qk_out, partial, C, nch);
  hipLaunchKernelGGL(caps_reduce, dim3(B_ * M_ * D_ / 256), dim3(256), 0, stream,
                     partial, nact, out, nch);
}

// Round 11
// 374.300 us; speedup vs baseline: 1.2986x; 1.2986x over previous
//
#include <hip/hip_runtime.h>
#include <stdint.h>
#include <stddef.h>

// CapsuleFC: B=64, N_IN=2048, D_IN=16, N_OUT=64, D_OUT=16
constexpr int B_ = 64, N_ = 2048, A_ = 16, M_ = 64, D_ = 16;
constexpr float SCALE_ = 0.25f;   // 1/sqrt(16)
constexpr float EPS_ = 1e-6f;

typedef float f32x4 __attribute__((ext_vector_type(4)));

#define GL16(g, l)                                                             \
  __builtin_amdgcn_global_load_lds((__attribute__((address_space(1))) void*)(g), \
                                   (__attribute__((address_space(3))) void*)(l), \
                                   16, 0, 0)

// Stage a-half HH (8 planes, 32KB) of w[NN] into wl[BUF].
// LDS dest linear (wave-uniform base); global SOURCE pre-swizzled
// (involution bits[6:4] ^= bits[9:7]) -> bank-balanced ds_read_b128 later.
#define STAGE(BUF, NN, HH)                                                     \
  { const char* ws_ = (const char*)w + ((size_t)(NN) << 16) + ((size_t)(HH) << 15); \
    char* lb_ = (char*)wl[BUF] + wv * 1024;                                    \
    _Pragma("unroll")                                                          \
    for (int i_ = 0; i_ < 8; ++i_) {                                           \
      const uint32_t P_ = (uint32_t)(i_ * 4096 + tid * 16);                    \
      const uint32_t S_ = P_ ^ (((P_ >> 7) & 7u) << 4);                        \
      GL16(ws_ + S_, lb_ + i_ * 4096);                                         \
    } }

// Accumulate votes for a-half HH of row n from wl[BUF] (R8 inner loop verbatim)
#define COMPUTE_HALF(BUF, NN, HH)                                              \
  { const char* lb_ = (const char*)wl[BUF];                                    \
    float ib_[4][8];                                                           \
    _Pragma("unroll")                                                          \
    for (int bi = 0; bi < 4; ++bi) {                                           \
      const int ibase_ = __builtin_amdgcn_readfirstlane(                       \
          ((b0 + bi) * N_ + (NN)) * A_ + (HH) * 8);                            \
      const f32x4 r0_ = *(const f32x4*)(input + ibase_);                       \
      const f32x4 r1_ = *(const f32x4*)(input + ibase_ + 4);                   \
      ib_[bi][0] = r0_.x; ib_[bi][1] = r0_.y; ib_[bi][2] = r0_.z; ib_[bi][3] = r0_.w; \
      ib_[bi][4] = r1_.x; ib_[bi][5] = r1_.y; ib_[bi][6] = r1_.z; ib_[bi][7] = r1_.w; \
    }                                                                          \
    _Pragma("unroll")                                                          \
    for (int al = 0; al < 8; ++al) {                                           \
      f32x4 wr_[4];                                                            \
      _Pragma("unroll")                                                        \
      for (int j = 0; j < 4; ++j)                                              \
        wr_[j] = *(const f32x4*)(lb_ + al * 4096 + offj[j]);                   \
      _Pragma("unroll")                                                        \
      for (int bi = 0; bi < 4; ++bi) {                                         \
        const float x_ = ib_[bi][al];                                          \
        _Pragma("unroll")                                                      \
        for (int j = 0; j < 4; ++j) {                                          \
          v[bi][4*j+0] += x_ * wr_[j].x; v[bi][4*j+1] += x_ * wr_[j].y;        \
          v[bi][4*j+2] += x_ * wr_[j].z; v[bi][4*j+3] += x_ * wr_[j].w;        \
        }                                                                      \
      }                                                                        \
    } }

// grid: 4*nch blocks (nch=256 -> 1024 blocks). block: 256 threads = 4 waves;
// wave wv owns 4 batches (b0 = bg*16 + wv*4); lane l owns out-capsule m = l.
//
// R10 lesson (3rd occurrence): inline-asm fences/counted-vmcnt -> regalloc
// failure -> scratch spills (WRITE 632MB, 486us). R8's plain structure is
// the regalloc sweet spot but drains vmcnt(0) RIGHT AFTER issuing the stage
// (full latency exposed, 4 barriers/n). This kernel = R8 with the T3
// minimum-2-phase reorder: double-buffered 32KB halves, STAGE(next) issued
// BEFORE COMPUTE(current), ONE __syncthreads per half -> the drain at the
// barrier is warm (loads aged under ~1-2us of compute >> ~900cy latency).
// No inline asm, no extra registers, static buffer indices.
__global__ __launch_bounds__(256, 2)
void caps_main(
    const float* __restrict__ input,   // [B,N,A]
    const float* __restrict__ cact,    // [B,N]
    const float* __restrict__ ncv,     // [B,M,D]
    const float* __restrict__ nact,    // [B,M]
    const float* __restrict__ w,       // [N,A,M,D]
    float* __restrict__ qk_out,        // [B,N,M]
    float* __restrict__ partial,       // [nch,B,M,D]
    int C, int nch)
{
  __shared__ __align__(128) char wl[2][32768];  // double-buffered a-half slabs

  const int tid  = threadIdx.x;
  const int lane = tid & 63;
  const int wv   = __builtin_amdgcn_readfirstlane(tid >> 6);

  // co-XCD mapping: the 4 bgroup-sharers of chunk ch land on xcd = flat&7
  const int flat = blockIdx.x;
  int bg, ch;
  if (nch & 7) { bg = flat & 3; ch = flat >> 2; }
  else { bg = (flat >> 3) & 3; ch = ((flat >> 5) << 3) | (flat & 7); }

  const int b0 = bg * 16 + wv * 4;
  const int n0 = ch * C;

  // swizzled LDS read offsets (pairs with stage-side source involution)
  int offj[4];
#pragma unroll
  for (int j = 0; j < 4; ++j)
    offj[j] = (lane * 64 + j * 16) ^ (((lane >> 1) & 7) << 4);

  // loop-invariant per-(b,m) values in registers
  float na[4], cv[4][16];
#pragma unroll
  for (int bi = 0; bi < 4; ++bi) {
    na[bi] = nact[(b0 + bi) * M_ + lane];
    const f32x4* np4 = (const f32x4*)(ncv + ((size_t)(b0 + bi) * M_ + lane) * D_);
#pragma unroll
    for (int j = 0; j < 4; ++j) {
      const f32x4 t = np4[j];
      cv[bi][4*j+0] = t.x; cv[bi][4*j+1] = t.y;
      cv[bi][4*j+2] = t.z; cv[bi][4*j+3] = t.w;
    }
  }

  float acc[4][16];
#pragma unroll
  for (int bi = 0; bi < 4; ++bi)
#pragma unroll
    for (int d = 0; d < 16; ++d) acc[bi][d] = 0.f;

  // ---- prologue: stage n0's half 0 into buf0 (cold drain, once)
  STAGE(0, n0, 0);
  __syncthreads();

  for (int k = 0; k < C; ++k) {
    const int n = n0 + k;

    float v[4][16];
#pragma unroll
    for (int bi = 0; bi < 4; ++bi)
#pragma unroll
      for (int d = 0; d < 16; ++d) v[bi][d] = 0.f;

    // phase A: issue next stage FIRST, then compute current (hides latency)
    STAGE(1, n, 1);
    COMPUTE_HALF(0, n, 0);
    __syncthreads();   // buf1 ready (warm drain); all waves done with buf0

    if (k + 1 < C) { STAGE(0, n + 1, 0); }
    COMPUTE_HALF(1, n, 1);

    // ---- scores -> wave-local softmax (m = lane) -> qk -> accumulate
#pragma unroll
    for (int bi = 0; bi < 4; ++bi) {
      float s = 0.f;
#pragma unroll
      for (int d = 0; d < 16; ++d) s += v[bi][d] * cv[bi][d];
      s *= SCALE_;
      // |s| small (~N(0,0.2)); max-subtraction cancels in the ratio -> skip
      const float e = __expf(s);
      const float ena = e * na[bi];
      float Ps = ena;
#pragma unroll
      for (int off = 32; off >= 1; off >>= 1) Ps += __shfl_xor(Ps, off, 64);
      const float qk = ena / Ps;   // 1e-10 terms ~2e-10 relative: dropped
      qk_out[((size_t)(b0 + bi) * N_ + n) * M_ + lane] = qk;
      float ab = cact[__builtin_amdgcn_readfirstlane((b0 + bi) * N_ + n)];
      ab = fminf(fmaxf(ab, EPS_), 1.0f - EPS_);
      const float wq = qk * ab;
#pragma unroll
      for (int d = 0; d < 16; ++d) acc[bi][d] += wq * v[bi][d];
    }

    __syncthreads();   // buf0 ready for next k (warm); all waves done w/ buf1
  }

  // partial[ch][b][m][d]
#pragma unroll
  for (int bi = 0; bi < 4; ++bi) {
    float* pp = partial + (((size_t)ch * B_ + (b0 + bi)) * M_ + lane) * D_;
#pragma unroll
    for (int j = 0; j < 4; ++j) {
      f32x4 t;
      t.x = acc[bi][4*j+0]; t.y = acc[bi][4*j+1];
      t.z = acc[bi][4*j+2]; t.w = acc[bi][4*j+3];
      __builtin_nontemporal_store(t, (f32x4*)pp + j);
    }
  }
}

__global__ void caps_reduce(const float* __restrict__ part,
                            const float* __restrict__ nain,
                            float* __restrict__ out, int nch)
{
  const int i = blockIdx.x * 256 + threadIdx.x;  // one thread per out[b,m,d]
  float s = 0.f;
  for (int c = 0; c < nch; ++c) s += part[(size_t)c * (B_ * M_ * D_) + i];
  out[i] = s;
  if (i < B_ * M_) out[B_ * M_ * D_ + i] = nain[i];  // next_act passthrough
}

extern "C" void kernel_launch(void* const* d_in, const int* in_sizes, int n_in,
                              void* d_out, int out_size, void* d_ws, size_t ws_size,
                              hipStream_t stream)
{
  const float* input = (const float*)d_in[0];
  const float* cact  = (const float*)d_in[1];
  const float* ncv   = (const float*)d_in[2];
  const float* nact  = (const float*)d_in[3];
  const float* w     = (const float*)d_in[4];

  float* out     = (float*)d_out;
  float* qk_out  = out + (B_ * M_ * D_) + (B_ * M_);   // after out and next_act
  float* partial = (float*)d_ws;

  // nch=256 -> grid 1024; needs 67MB ws; degrade if smaller
  int nch = 256;
  while ((size_t)nch * (size_t)(B_ * M_ * D_) * sizeof(float) > ws_size && nch > 32) nch >>= 1;
  const int C = N_ / nch;

  hipLaunchKernelGGL(caps_main, dim3(4 * nch), dim3(256), 0, stream,
                     input, cact, ncv, nact, w, qk_out, partial, C, nch);
  hipLaunchKernelGGL(caps_reduce, dim3(B_ * M_ * D_ / 256), dim3(256), 0, stream,
                     partial, nact, out, nch);
}